// Round 1
// baseline (432.798 us; speedup 1.0000x reference)
//
#include <hip/hip_runtime.h>

#define LSZ 8192
#define CCH 32
#define NL 8                 // positions per block (1 per wave, 8 waves)
#define TILE_P (NL + 3)      // halo: need p in [l0-2, l0+NL]

// out[b,l,f] = 2*bias[l,f] + sum_i sum_c xin[b, (l-step_i) mod L, c] * w[i,l,c,f]
// then BN(gamma,beta,mean,var; eps=1e-3), then (optionally +xres), LeakyReLU(0.3)
__global__ __launch_bounds__(512)
void lc_bn_act(const float* __restrict__ xin,
               const float* __restrict__ wgt,     // [5][L][32][32]
               const float* __restrict__ bias,    // [L][32]
               const float* __restrict__ gamma,
               const float* __restrict__ beta,
               const float* __restrict__ mean,
               const float* __restrict__ var,
               const float* __restrict__ xres,
               float* __restrict__ out,
               int resid)
{
    __shared__ __align__(16) float lds[TILE_P * 32 * 32];
    const int tid = threadIdx.x;
    const int l0  = blockIdx.x * NL;

    // ---- stage xin tile [tp][c][swz(b)]  (transpose with b-quad XOR swizzle) ----
    #pragma unroll
    for (int it = 0; it < (TILE_P * 1024) / 512; ++it) {
        int flat = it * 512 + tid;
        int c  = flat & 31;
        int b  = (flat >> 5) & 31;
        int tp = flat >> 10;
        int p  = (l0 + LSZ - 2 + tp) & (LSZ - 1);
        float v = xin[((size_t)b * LSZ + p) * CCH + c];
        int swz = (((b >> 2) ^ (c & 7)) << 2) | (b & 3);
        lds[tp * 1024 + c * 32 + swz] = v;
    }
    __syncthreads();

    const int wl   = tid >> 6;     // wave id = l offset in tile
    const int lane = tid & 63;
    const int fi   = lane & 7;     // f = 4*fi .. 4*fi+3
    const int bg   = lane >> 3;    // b = 4*bg .. 4*bg+3
    const int l    = l0 + wl;

    float4 acc0 = {0.f,0.f,0.f,0.f};
    float4 acc1 = {0.f,0.f,0.f,0.f};
    float4 acc2 = {0.f,0.f,0.f,0.f};
    float4 acc3 = {0.f,0.f,0.f,0.f};

    const int stepArr[5] = {0, 0, 1, -1, 2};

    #pragma unroll
    for (int i = 0; i < 5; ++i) {
        const int tp = wl + 2 - stepArr[i];          // in [0, TILE_P)
        const float* wp = wgt + (((size_t)i * LSZ + l) << 10) + (fi << 2);
        const float* xp = lds + tp * 1024;
        #pragma unroll 8
        for (int c = 0; c < 32; ++c) {
            float4 w4 = *reinterpret_cast<const float4*>(wp + (c << 5));
            float4 x4 = *reinterpret_cast<const float4*>(xp + (c << 5) + ((bg ^ (c & 7)) << 2));
            acc0.x = fmaf(x4.x, w4.x, acc0.x); acc0.y = fmaf(x4.x, w4.y, acc0.y);
            acc0.z = fmaf(x4.x, w4.z, acc0.z); acc0.w = fmaf(x4.x, w4.w, acc0.w);
            acc1.x = fmaf(x4.y, w4.x, acc1.x); acc1.y = fmaf(x4.y, w4.y, acc1.y);
            acc1.z = fmaf(x4.y, w4.z, acc1.z); acc1.w = fmaf(x4.y, w4.w, acc1.w);
            acc2.x = fmaf(x4.z, w4.x, acc2.x); acc2.y = fmaf(x4.z, w4.y, acc2.y);
            acc2.z = fmaf(x4.z, w4.z, acc2.z); acc2.w = fmaf(x4.z, w4.w, acc2.w);
            acc3.x = fmaf(x4.w, w4.x, acc3.x); acc3.y = fmaf(x4.w, w4.y, acc3.y);
            acc3.z = fmaf(x4.w, w4.z, acc3.z); acc3.w = fmaf(x4.w, w4.w, acc3.w);
        }
    }

    // ---- epilogue: 2*bias, BN, (residual), leaky ----
    const int f0 = fi << 2;
    float4 g4 = *reinterpret_cast<const float4*>(gamma + f0);
    float4 t4 = *reinterpret_cast<const float4*>(beta  + f0);
    float4 m4 = *reinterpret_cast<const float4*>(mean  + f0);
    float4 v4 = *reinterpret_cast<const float4*>(var   + f0);
    float4 sc, sh;
    sc.x = g4.x * rsqrtf(v4.x + 1e-3f); sh.x = t4.x - m4.x * sc.x;
    sc.y = g4.y * rsqrtf(v4.y + 1e-3f); sh.y = t4.y - m4.y * sc.y;
    sc.z = g4.z * rsqrtf(v4.z + 1e-3f); sh.z = t4.z - m4.z * sc.z;
    sc.w = g4.w * rsqrtf(v4.w + 1e-3f); sh.w = t4.w - m4.w * sc.w;
    float4 bb = *reinterpret_cast<const float4*>(bias + l * 32 + f0);

#define EPILOG(ACC, J)                                                          \
    {                                                                           \
        int b = (bg << 2) + (J);                                                \
        size_t off = ((size_t)b * LSZ + l) * 32 + f0;                           \
        float4 t;                                                               \
        t.x = (ACC.x + 2.f * bb.x) * sc.x + sh.x;                               \
        t.y = (ACC.y + 2.f * bb.y) * sc.y + sh.y;                               \
        t.z = (ACC.z + 2.f * bb.z) * sc.z + sh.z;                               \
        t.w = (ACC.w + 2.f * bb.w) * sc.w + sh.w;                               \
        if (resid) {                                                            \
            float4 r = *reinterpret_cast<const float4*>(xres + off);            \
            t.x += r.x; t.y += r.y; t.z += r.z; t.w += r.w;                     \
        }                                                                       \
        t.x = t.x >= 0.f ? t.x : 0.3f * t.x;                                    \
        t.y = t.y >= 0.f ? t.y : 0.3f * t.y;                                    \
        t.z = t.z >= 0.f ? t.z : 0.3f * t.z;                                    \
        t.w = t.w >= 0.f ? t.w : 0.3f * t.w;                                    \
        *reinterpret_cast<float4*>(out + off) = t;                              \
    }

    EPILOG(acc0, 0)
    EPILOG(acc1, 1)
    EPILOG(acc2, 2)
    EPILOG(acc3, 3)
#undef EPILOG
}

extern "C" void kernel_launch(void* const* d_in, const int* in_sizes, int n_in,
                              void* d_out, int out_size, void* d_ws, size_t ws_size,
                              hipStream_t stream) {
    const float* x   = (const float*)d_in[0];
    const float* k1  = (const float*)d_in[1];
    const float* b1  = (const float*)d_in[2];
    const float* g1  = (const float*)d_in[3];
    const float* be1 = (const float*)d_in[4];
    const float* mn1 = (const float*)d_in[5];
    const float* vr1 = (const float*)d_in[6];
    const float* k2  = (const float*)d_in[7];
    const float* b2  = (const float*)d_in[8];
    const float* g2  = (const float*)d_in[9];
    const float* be2 = (const float*)d_in[10];
    const float* mn2 = (const float*)d_in[11];
    const float* vr2 = (const float*)d_in[12];

    float* h = (float*)d_ws;                 // [32][8192][32] intermediate
    float* o = (float*)d_out;

    dim3 grid(LSZ / NL), block(512);
    hipLaunchKernelGGL(lc_bn_act, grid, block, 0, stream,
                       x, k1, b1, g1, be1, mn1, vr1, x, h, 0);
    hipLaunchKernelGGL(lc_bn_act, grid, block, 0, stream,
                       h, k2, b2, g2, be2, mn2, vr2, x, o, 1);
}